// Round 18
// baseline (164.748 us; speedup 1.0000x reference)
//
#include <hip/hip_runtime.h>
#include <stdint.h>

typedef unsigned short u16;
typedef __bf16 bf16x8 __attribute__((ext_vector_type(8)));
typedef float f32x4 __attribute__((ext_vector_type(4)));
typedef unsigned short ushort8 __attribute__((ext_vector_type(8)));
typedef unsigned short ushort4v __attribute__((ext_vector_type(4)));
typedef uint32_t uint4v __attribute__((ext_vector_type(4)));

#define MFMA __builtin_amdgcn_mfma_f32_16x16x32_bf16
#define EXP2 __builtin_amdgcn_exp2f

__device__ __forceinline__ u16 f2bf(float f){
  uint32_t u = __builtin_bit_cast(uint32_t, f);
  u += 0x7fffu + ((u >> 16) & 1u);
  return (u16)(u >> 16);
}
__device__ __forceinline__ float bf2f(u16 h){
  uint32_t u = ((uint32_t)h) << 16;
  return __builtin_bit_cast(float, u);
}
__device__ __forceinline__ uint32_t cvtpk(float lo, float hi){
  uint32_t r;
  asm("v_cvt_pk_bf16_f32 %0, %1, %2" : "=v"(r) : "v"(lo), "v"(hi));
  return r;
}
__device__ __forceinline__ bf16x8 ld8(const u16* p){
  return __builtin_bit_cast(bf16x8, *(const ushort8*)p);
}
__device__ __forceinline__ void gload16(const void* g, void* l){
  __builtin_amdgcn_global_load_lds((__attribute__((address_space(1))) void*)(void*)g,
                                   (__attribute__((address_space(3))) void*)l, 16, 0, 0);
}

// ---------------- fused preprocessing: conv8 | tr(qkv_w) | tr(proj_w) | relconv ----------------

__device__ __forceinline__ void tr_body(const float* __restrict__ in, u16* __restrict__ out,
                                        int R, int Cc, int bx, int by, int t, float* tile /*64x65*/){
  int r0 = bx*64, c0 = by*64;
  int c = t & 63, r4 = t >> 6;
  for (int i = 0; i < 16; ++i)
    tile[(r4 + i*4)*65 + c] = in[(size_t)(r0 + r4 + i*4)*Cc + c0 + c];
  __syncthreads();
  for (int i = 0; i < 16; ++i){
    int rr = r4 + i*4;
    out[(size_t)(c0 + rr)*R + r0 + c] = f2bf(tile[c*65 + rr]);
  }
}

__global__ __launch_bounds__(256) void k_prep(const float* __restrict__ X32,
                                              const float* __restrict__ qkvw,
                                              const float* __restrict__ projw,
                                              const float* __restrict__ rposh,
                                              const float* __restrict__ rposw,
                                              u16* __restrict__ Xb, u16* __restrict__ W1T,
                                              u16* __restrict__ PT,
                                              u16* __restrict__ rh8, u16* __restrict__ rw8){
  __shared__ float tile[64*65];
  const int b = blockIdx.x, t = threadIdx.x;
  if (b < 1536){
    int i = b*256 + t;
    const float4* p = (const float4*)X32;
    float4 a = p[i*2], c = p[i*2+1];
    ushort8 o;
    o[0]=f2bf(a.x); o[1]=f2bf(a.y); o[2]=f2bf(a.z); o[3]=f2bf(a.w);
    o[4]=f2bf(c.x); o[5]=f2bf(c.y); o[6]=f2bf(c.z); o[7]=f2bf(c.w);
    ((ushort8*)Xb)[i] = o;
  } else if (b < 1968){
    int bb = b - 1536;
    tr_body(qkvw, W1T, 768, 2304, bb % 12, bb / 12, t, tile);
  } else if (b < 2112){
    int bb = b - 1968;
    tr_body(projw, PT, 768, 768, bb % 12, bb / 12, t, tile);
  } else {
    int i = (b - 2112)*256 + t;          // [0,16384)
    if (i < 8192)      rh8[i] = f2bf(i < 8128 ? rposh[i]*8.0f : 0.0f);
    else { int j = i - 8192; rw8[j] = f2bf(j < 8128 ? rposw[j]*8.0f : 0.0f); }
  }
}

// ---------------- QKV GEMM: (4096x768)x(768x2304), split to Qs/Kf/Vf ----------------
// K fragment-linear:  Kf[h][kb][f=ct*2+ks][lane=lg*16+lr][e] = K[kb*64+ct*16+lr][ks*32+lg*8+e]
// V fragment-linear with PERMUTED k (pi(lg,e) = (e>>2)*16 + lg*4 + (e&3)) so the
// flash PV B-operand can be assembled IN-REGISTER from the swapped-QK^T output.

__global__ __launch_bounds__(256) void k_qkv(const u16* __restrict__ X, const u16* __restrict__ WT,
                                             const float* __restrict__ bias,
                                             u16* __restrict__ Qs, u16* __restrict__ Kf, u16* __restrict__ Vf){
  __shared__ __align__(16) u16 At[128*64];
  __shared__ __align__(16) u16 Bt[128*64];
  __shared__ __align__(16) u16 Tt[4][64*72];   // per-wave repack tile, pad 72 keeps 16B align
  const int tid = threadIdx.x, lane = tid & 63, w = tid >> 6;
  const int m0 = blockIdx.x*128, n0 = blockIdx.y*128;
  const int wr = (w >> 1)*64, wc = (w & 1)*64;
  const int lr = lane & 15, lg = lane >> 4;
  const int srcRow = w*32 + (lane >> 3);
  const int srcK   = (lane & 7)*8;
  f32x4 acc[4][4] = {};
  for (int kt = 0; kt < 12; ++kt){
    const int kbase = kt*64;
    for (int s = 0; s < 4; ++s){
      gload16(X  + (size_t)(m0 + srcRow + s*8)*768 + kbase + srcK, At + (w*32 + s*8)*64);
      gload16(WT + (size_t)(n0 + srcRow + s*8)*768 + kbase + srcK, Bt + (w*32 + s*8)*64);
    }
    __syncthreads();
    bf16x8 af[2][4], bfr[2][4];
    for (int ks = 0; ks < 2; ++ks)
      for (int i = 0; i < 4; ++i){
        af[ks][i]  = ld8(At + (wr + i*16 + lr)*64 + ks*32 + lg*8);
        bfr[ks][i] = ld8(Bt + (wc + i*16 + lr)*64 + ks*32 + lg*8);
      }
    for (int ks = 0; ks < 2; ++ks)
      for (int mi = 0; mi < 4; ++mi)
        for (int ni = 0; ni < 4; ++ni)
          acc[mi][ni] = MFMA(af[ks][mi], bfr[ks][ni], acc[mi][ni], 0, 0, 0);
    __syncthreads();
  }
  const int colbase = n0 + wc;            // 64-aligned -> s3/hh uniform per wave
  const int s3 = colbase / 768;
  const int hh = (colbase % 768) >> 6;
  const int rowbase = m0 + wr;            // 64-aligned -> kb uniform per wave
  if (s3 == 0){
    for (int mi = 0; mi < 4; ++mi)
      for (int ni = 0; ni < 4; ++ni){
        float bv = bias[colbase + ni*16 + lr];
        for (int r = 0; r < 4; ++r){
          int row = rowbase + mi*16 + lg*4 + r;
          // Q pre-scaled by head_dim^-0.5 * log2(e) so softmax runs in exp2 domain
          Qs[((size_t)hh*4096 + row)*64 + ni*16 + lr] =
              f2bf((acc[mi][ni][r] + bv)*(0.125f*1.44269504f));
        }
      }
  } else {
    u16* T = Tt[w];
    for (int mi = 0; mi < 4; ++mi)
      for (int ni = 0; ni < 4; ++ni){
        float bv = bias[colbase + ni*16 + lr];
        for (int r = 0; r < 4; ++r){
          int row_l = mi*16 + lg*4 + r, col_l = ni*16 + lr;
          u16 v = f2bf(acc[mi][ni][r] + bv);
          if (s3 == 1) T[row_l*72 + col_l] = v;     // K: [token][d]
          else         T[col_l*72 + row_l] = v;     // V: [d][token] (transposed)
        }
      }
    // same-wave LDS write->read; no cross-wave sharing, compiler inserts lgkmcnt
    const int kb = rowbase >> 6;
    u16* dst = (s3 == 1 ? Kf : Vf) + ((size_t)hh*64 + kb)*4096 + lane*8;
    if (s3 == 1){
      #pragma unroll
      for (int f = 0; f < 8; ++f){
        int a = f >> 1, ks = f & 1;
        *(ushort8*)&dst[f*512] = *(const ushort8*)&T[(a*16 + lr)*72 + ks*32 + lg*8];
      }
    } else {
      // permuted-k V fragments: elems 0-3 <- tokens ks*32+lg*4+(0..3),
      //                         elems 4-7 <- tokens ks*32+16+lg*4+(0..3)
      #pragma unroll
      for (int f = 0; f < 8; ++f){
        int a = f >> 1, ks = f & 1;
        const int rowb = (a*16 + lr)*72 + ks*32 + lg*4;
        ushort4v lo = *(const ushort4v*)&T[rowb];
        ushort4v hi = *(const ushort4v*)&T[rowb + 16];
        ushort8 o;
        o[0]=lo[0]; o[1]=lo[1]; o[2]=lo[2]; o[3]=lo[3];
        o[4]=hi[0]; o[5]=hi[1]; o[6]=hi[2]; o[7]=hi[3];
        *(ushort8*)&dst[f*512] = o;
      }
    }
  }
}

// ---------------- rel_h / rel_w via MFMA; grid (64 qh, 12 h) ----------------

__global__ __launch_bounds__(256) void k_rel(const u16* __restrict__ Qs, const u16* __restrict__ Rh8,
                                             const u16* __restrict__ Rw8,
                                             u16* __restrict__ relh, u16* __restrict__ relw){
  __shared__ __align__(16) u16 Ql[64*64];
  __shared__ __align__(16) u16 Rhl[64*64];
  __shared__ __align__(16) u16 Rwl[128*64];
  const int tid = threadIdx.x, lane = tid & 63, w = tid >> 6;
  const int qh = blockIdx.x, h = blockIdx.y;
  const int lr = lane & 15, lg = lane >> 4;
  for (int j = 0; j < 2; ++j){
    int ch = tid + 256*j;             // 0..511
    int row = ch >> 3, k8 = (ch & 7)*8;
    *(ushort8*)&Ql[row*64 + k8]  = *(const ushort8*)&Qs[((size_t)h*4096 + qh*64 + row)*64 + k8];
    *(ushort8*)&Rhl[row*64 + k8] = *(const ushort8*)&Rh8[(qh + row)*64 + k8];
  }
  for (int j = 0; j < 4; ++j){
    int ch = tid + 256*j;             // 0..1023
    int row = ch >> 3, k8 = (ch & 7)*8;
    *(ushort8*)&Rwl[row*64 + k8] = *(const ushort8*)&Rw8[row*64 + k8];
  }
  __syncthreads();
  bf16x8 a[2];
  for (int ks = 0; ks < 2; ++ks) a[ks] = ld8(Ql + (w*16 + lr)*64 + ks*32 + lg*8);
  // rel_h[qw][kh] = (Q . rel_pos_h[qh+63-kh]) ; computed as Q @ Rh[qh+c]^T, kh = 63-c
  for (int ct = 0; ct < 4; ++ct){
    f32x4 c = {};
    for (int ks = 0; ks < 2; ++ks)
      c = MFMA(a[ks], ld8(Rhl + (ct*16 + lr)*64 + ks*32 + lg*8), c, 0, 0, 0);
    int kh = 63 - (ct*16 + lr);
    for (int r = 0; r < 4; ++r){
      int qw = w*16 + lg*4 + r;
      relh[((size_t)h*4096 + qh*64 + qw)*64 + kh] = f2bf(c[r]);
    }
  }
  // rel_w[qw][kw] = (Q . rel_pos_w[qw+63-kw]) ; full band, keep valid kw
  for (int ct = 0; ct < 8; ++ct){
    f32x4 c = {};
    for (int ks = 0; ks < 2; ++ks)
      c = MFMA(a[ks], ld8(Rwl + (ct*16 + lr)*64 + ks*32 + lg*8), c, 0, 0, 0);
    int cc = ct*16 + lr;
    for (int r = 0; r < 4; ++r){
      int qw = w*16 + lg*4 + r;
      int kw = qw + 63 - cc;
      if (kw >= 0 && kw < 64)
        relw[((size_t)h*4096 + qh*64 + qw)*64 + kw] = f2bf(c[r]);
    }
  }
}

// ---------------- flash attention; flat grid 768, 4 waves ----------------
// R17 = R14 proven body (scalar lazy softmax, in-register P via permuted-k Vf)
// + T4 counted-vmcnt pipeline: __syncthreads drains vmcnt(0) (kills the
// 2-deep prefetch); replaced with asm s_waitcnt vmcnt(4) + raw s_barrier.
// FIFO retirement: <=4 outstanding => the current tile's 4 stage loads (the
// oldest) completed; compiler-issued extra VMEM (rhbase) only makes the wait
// more conservative. Last iteration peeled with vmcnt(0). sched_barrier(0)
// after each wait/barrier pins MFMA/ds_read ordering (rule #18).
// Head->XCD affinity (768 = 8*96): <=2 heads (2MB KV) per XCD L2.
// launch_bounds(256,3): arch-VGPR budget ~84; spill tripwire = FETCH_SIZE.

__global__ __launch_bounds__(256, 3) void k_flash(const u16* __restrict__ Qs, const u16* __restrict__ Kf,
                                                  const u16* __restrict__ Vf,
                                                  const u16* __restrict__ relh, const u16* __restrict__ relw,
                                                  u16* __restrict__ Ob){
  __shared__ __align__(16) u16 Kl[2][4096];       // 8KB per K tile (fragment-linear copy)
  __shared__ __align__(16) u16 Vl[2][4096];       // 8KB per V tile (permuted-k layout)
  const int tid = threadIdx.x, lane = tid & 63, w = tid >> 6;
  const int b = blockIdx.x;
  const int p = (b & 7)*96 + (b >> 3);         // head->XCD affinity remap (768 = 8*96)
  const int h = p >> 6, qb = p & 63;
  const int lr = lane & 15, lg = lane >> 4;
  const size_t hq = (size_t)h*4096;
  const int q = qb*64 + w*16 + lr;             // this lane's q row (S^T column)

  const bf16x8 qf0 = ld8(Qs + (hq + q)*64 + lg*8);
  const bf16x8 qf1 = ld8(Qs + (hq + q)*64 + 32 + lg*8);
  // rel_w bias row unpacked to f32 once
  float rwf[4][4];
  #pragma unroll
  for (int ct = 0; ct < 4; ++ct){
    ushort4v t = *(const ushort4v*)&relw[(hq + q)*64 + ct*16 + lg*4];
    #pragma unroll
    for (int r = 0; r < 4; ++r) rwf[ct][r] = bf2f(t[r]);
  }

  const u16* KfH = Kf + (size_t)h*262144;      // + kb*4096
  const u16* VfH = Vf + (size_t)h*262144;
  const u16* rhbase = relh + (hq + q)*64;

  float m = -1e30f, lsum = 0.f;                // lsum per-lane partial (reduced at end)
  f32x4 oacc[4] = {};                          // O^T: rows d = dt*16+lg*4+r, col q = lr

  // wave w stages 1KB chunks {2w, 2w+1} of K and V (8 chunks each, 4 waves).
  auto stage = [&](int buf, int kb){
    const u16* ks = KfH + kb*4096 + w*1024 + lane*8;
    const u16* vs = VfH + kb*4096 + w*1024 + lane*8;
    gload16(ks,       &Kl[buf][w*1024]);
    gload16(ks + 512, &Kl[buf][w*1024 + 512]);
    gload16(vs,       &Vl[buf][w*1024]);
    gload16(vs + 512, &Vl[buf][w*1024 + 512]);
  };

#define ITERBODY(KB, BUF)                                                     \
  {                                                                           \
    const u16* KL = Kl[BUF] + lane*8;                                         \
    const u16* VL = Vl[BUF] + lane*8;                                         \
    const float rhv = bf2f(rhbase[KB]);                                       \
    f32x4 s[4];                                                               \
    _Pragma("unroll")                                                         \
    for (int ct = 0; ct < 4; ++ct){                                           \
      _Pragma("unroll")                                                       \
      for (int r = 0; r < 4; ++r) s[ct][r] = rhv + rwf[ct][r];                \
    }                                                                         \
    __builtin_amdgcn_s_setprio(1);                                            \
    _Pragma("unroll")                                                         \
    for (int ct = 0; ct < 4; ++ct){                                           \
      s[ct] = MFMA(ld8(KL + (ct*2)*512),   qf0, s[ct], 0, 0, 0);              \
      s[ct] = MFMA(ld8(KL + (ct*2+1)*512), qf1, s[ct], 0, 0, 0);              \
    }                                                                         \
    __builtin_amdgcn_s_setprio(0);                                            \
    /* lane-local max over own 16 values */                                   \
    float pm0 = fmaxf(fmaxf(s[0][0], s[0][1]), fmaxf(fmaxf(s[0][2], s[0][3]), \
                      fmaxf(s[1][0], s[1][1])));                              \
    float pm1 = fmaxf(fmaxf(s[1][2], s[1][3]), fmaxf(fmaxf(s[2][0], s[2][1]), \
                      fmaxf(s[2][2], s[2][3])));                              \
    float pm2 = fmaxf(fmaxf(s[3][0], s[3][1]), fmaxf(s[3][2], s[3][3]));      \
    float pm = fmaxf(fmaxf(pm0, pm1), pm2);                                   \
    /* lazy rescale: cross-lane reduce only when some row max grew */         \
    if (__any(pm > m)){                                                       \
      pm = fmaxf(pm, __shfl_xor(pm, 16, 64));                                 \
      pm = fmaxf(pm, __shfl_xor(pm, 32, 64));                                 \
      const float nm = fmaxf(m, pm);                                          \
      const float corr = EXP2(m - nm);                                        \
      m = nm;                                                                 \
      lsum *= corr;                                                           \
      _Pragma("unroll")                                                       \
      for (int dt = 0; dt < 4; ++dt)                                          \
        _Pragma("unroll")                                                     \
        for (int r = 0; r < 4; ++r) oacc[dt][r] *= corr;                      \
    }                                                                         \
    float rs = 0.f;                                                           \
    _Pragma("unroll")                                                         \
    for (int ct = 0; ct < 4; ++ct){                                           \
      _Pragma("unroll")                                                       \
      for (int r = 0; r < 4; ++r){                                            \
        float p2 = EXP2(s[ct][r] - m);                                        \
        s[ct][r] = p2; rs += p2;                                              \
      }                                                                       \
    }                                                                         \
    lsum += rs;   /* per-lane partial; no shfl here */                        \
    /* P^T B-fragments in-register (k-permuted to match Vf layout) */         \
    uint4v u0, u1;                                                            \
    u0[0] = cvtpk(s[0][0], s[0][1]); u0[1] = cvtpk(s[0][2], s[0][3]);         \
    u0[2] = cvtpk(s[1][0], s[1][1]); u0[3] = cvtpk(s[1][2], s[1][3]);         \
    u1[0] = cvtpk(s[2][0], s[2][1]); u1[1] = cvtpk(s[2][2], s[2][3]);         \
    u1[2] = cvtpk(s[3][0], s[3][1]); u1[3] = cvtpk(s[3][2], s[3][3]);         \
    bf16x8 pa0 = __builtin_bit_cast(bf16x8, u0);                              \
    bf16x8 pa1 = __builtin_bit_cast(bf16x8, u1);                              \
    __builtin_amdgcn_s_setprio(1);                                            \
    _Pragma("unroll")                                                         \
    for (int dt = 0; dt < 4; ++dt){                                           \
      oacc[dt] = MFMA(ld8(VL + (dt*2)*512),   pa0, oacc[dt], 0, 0, 0);        \
      oacc[dt] = MFMA(ld8(VL + (dt*2+1)*512), pa1, oacc[dt], 0, 0, 0);        \
    }                                                                         \
    __builtin_amdgcn_s_setprio(0);                                            \
  }

  stage(0, 0);
  stage(1, 1);                         // prefetch depth 2: 8 outstanding/wave
  for (int t = 0; t < 63; ++t){
    asm volatile("s_waitcnt vmcnt(4)" ::: "memory");   // tile t's 4 loads done
    __builtin_amdgcn_s_barrier();
    __builtin_amdgcn_sched_barrier(0);
    ITERBODY(t, (t & 1))
    __builtin_amdgcn_s_barrier();      // all waves done reading buf (t&1)
    __builtin_amdgcn_sched_barrier(0);
    if (t < 62) stage(t & 1, t + 2);   // refill behind the pipeline
  }
  asm volatile("s_waitcnt vmcnt(0)" ::: "memory");
  __builtin_amdgcn_s_barrier();
  __builtin_amdgcn_sched_barrier(0);
  ITERBODY(63, 1)
#undef ITERBODY

  // epilogue: single cross-lane sum reduce of the per-lane lsum partials
  lsum += __shfl_xor(lsum, 16, 64);
  lsum += __shfl_xor(lsum, 32, 64);
  const float inv = 1.0f / lsum;
  #pragma unroll
  for (int dt = 0; dt < 4; ++dt){
    ushort4v pk;
    #pragma unroll
    for (int r = 0; r < 4; ++r) pk[r] = f2bf(oacc[dt][r]*inv);
    *(ushort4v*)&Ob[(size_t)q*768 + h*64 + dt*16 + lg*4] = pk;
  }
}

// ---------------- proj GEMM: (4096x768)x(768x768) + b -> f32 out ----------------

__global__ __launch_bounds__(256) void k_proj(const u16* __restrict__ A, const u16* __restrict__ WT,
                                              const float* __restrict__ bias, float* __restrict__ out){
  __shared__ __align__(16) u16 At[128*64];
  __shared__ __align__(16) u16 Bt[128*64];
  const int tid = threadIdx.x, lane = tid & 63, w = tid >> 6;
  const int m0 = blockIdx.x*128, n0 = blockIdx.y*128;
  const int wr = (w >> 1)*64, wc = (w & 1)*64;
  const int lr = lane & 15, lg = lane >> 4;
  const int srcRow = w*32 + (lane >> 3);
  const int srcK   = (lane & 7)*8;
  f32x4 acc[4][4] = {};
  for (int kt = 0; kt < 12; ++kt){
    const int kbase = kt*64;
    for (int s = 0; s < 4; ++s){
      gload16(A  + (size_t)(m0 + srcRow + s*8)*768 + kbase + srcK, At + (w*32 + s*8)*64);
      gload16(WT + (size_t)(n0 + srcRow + s*8)*768 + kbase + srcK, Bt + (w*32 + s*8)*64);
    }
    __syncthreads();
    bf16x8 af[2][4], bfr[2][4];
    for (int ks = 0; ks < 2; ++ks)
      for (int i = 0; i < 4; ++i){
        af[ks][i]  = ld8(At + (wr + i*16 + lr)*64 + ks*32 + lg*8);
        bfr[ks][i] = ld8(Bt + (wc + i*16 + lr)*64 + ks*32 + lg*8);
      }
    for (int ks = 0; ks < 2; ++ks)
      for (int mi = 0; mi < 4; ++mi)
        for (int ni = 0; ni < 4; ++ni)
          acc[mi][ni] = MFMA(af[ks][mi], bfr[ks][ni], acc[mi][ni], 0, 0, 0);
    __syncthreads();
  }
  for (int mi = 0; mi < 4; ++mi)
    for (int ni = 0; ni < 4; ++ni){
      int col = n0 + wc + ni*16 + lr;
      float bv = bias[col];
      for (int r = 0; r < 4; ++r){
        int row = m0 + wr + mi*16 + lg*4 + r;
        out[(size_t)row*768 + col] = acc[mi][ni][r] + bv;
      }
    }
}

// ---------------- launch ----------------

extern "C" void kernel_launch(void* const* d_in, const int* in_sizes, int n_in,
                              void* d_out, int out_size, void* d_ws, size_t ws_size,
                              hipStream_t stream){
  const float* X32   = (const float*)d_in[0];
  const float* qkvw  = (const float*)d_in[1];
  const float* qkvb  = (const float*)d_in[2];
  const float* projw = (const float*)d_in[3];
  const float* projb = (const float*)d_in[4];
  const float* rposh = (const float*)d_in[5];
  const float* rposw = (const float*)d_in[6];

  u16* Xb  = (u16*)d_ws;            // 4096*768
  u16* W1T = Xb  + 3145728;         // 2304*768
  u16* PT  = W1T + 1769472;         // 768*768
  u16* Rh8 = PT  + 589824;          // 128*64 (padded)
  u16* Rw8 = Rh8 + 8192;            // 128*64 (padded)
  u16* Qs  = Rw8 + 8192;            // 12*4096*64 (pre-scaled by 1/8 * log2e)
  u16* Kf  = Qs  + 3145728;         // fragment-linear K [12][64][8][64][8]
  u16* Vf  = Kf  + 3145728;         // fragment-linear V^T, k-permuted [12][64][8][64][8]
  u16* Rlh = Vf  + 3145728;         // [12][4096][64]
  u16* Rlw = Rlh + 3145728;         // [12][4096][64]
  u16* Ob  = Rlw + 3145728;         // [4096][768]
  float* out = (float*)d_out;

  k_prep <<<2176, 256, 0, stream>>>(X32, qkvw, projw, rposh, rposw, Xb, W1T, PT, Rh8, Rw8);
  k_qkv  <<<dim3(32, 18), 256, 0, stream>>>(Xb, W1T, qkvb, Qs, Kf, Vf);
  k_rel  <<<dim3(64, 12), 256, 0, stream>>>(Qs, Rh8, Rw8, Rlh, Rlw);
  k_flash<<<768, 256, 0, stream>>>(Qs, Kf, Vf, Rlh, Rlw, Ob);
  k_proj <<<dim3(32, 6), 256, 0, stream>>>(Ob, PT, projb, out);
}

// Round 19
// 164.476 us; speedup vs baseline: 1.0016x; 1.0016x over previous
//
#include <hip/hip_runtime.h>
#include <stdint.h>

typedef unsigned short u16;
typedef __bf16 bf16x8 __attribute__((ext_vector_type(8)));
typedef float f32x4 __attribute__((ext_vector_type(4)));
typedef unsigned short ushort8 __attribute__((ext_vector_type(8)));
typedef unsigned short ushort4v __attribute__((ext_vector_type(4)));
typedef uint32_t uint4v __attribute__((ext_vector_type(4)));

#define MFMA __builtin_amdgcn_mfma_f32_16x16x32_bf16
#define EXP2 __builtin_amdgcn_exp2f

__device__ __forceinline__ u16 f2bf(float f){
  uint32_t u = __builtin_bit_cast(uint32_t, f);
  u += 0x7fffu + ((u >> 16) & 1u);
  return (u16)(u >> 16);
}
__device__ __forceinline__ float bf2f(u16 h){
  uint32_t u = ((uint32_t)h) << 16;
  return __builtin_bit_cast(float, u);
}
__device__ __forceinline__ uint32_t cvtpk(float lo, float hi){
  uint32_t r;
  asm("v_cvt_pk_bf16_f32 %0, %1, %2" : "=v"(r) : "v"(lo), "v"(hi));
  return r;
}
__device__ __forceinline__ bf16x8 ld8(const u16* p){
  return __builtin_bit_cast(bf16x8, *(const ushort8*)p);
}
__device__ __forceinline__ void gload16(const void* g, void* l){
  __builtin_amdgcn_global_load_lds((__attribute__((address_space(1))) void*)(void*)g,
                                   (__attribute__((address_space(3))) void*)l, 16, 0, 0);
}

// ---------------- fused preprocessing: conv8 | tr(qkv_w) | tr(proj_w) | relconv ----------------

__device__ __forceinline__ void tr_body(const float* __restrict__ in, u16* __restrict__ out,
                                        int R, int Cc, int bx, int by, int t, float* tile /*64x65*/){
  int r0 = bx*64, c0 = by*64;
  int c = t & 63, r4 = t >> 6;
  for (int i = 0; i < 16; ++i)
    tile[(r4 + i*4)*65 + c] = in[(size_t)(r0 + r4 + i*4)*Cc + c0 + c];
  __syncthreads();
  for (int i = 0; i < 16; ++i){
    int rr = r4 + i*4;
    out[(size_t)(c0 + rr)*R + r0 + c] = f2bf(tile[c*65 + rr]);
  }
}

__global__ __launch_bounds__(256) void k_prep(const float* __restrict__ X32,
                                              const float* __restrict__ qkvw,
                                              const float* __restrict__ projw,
                                              const float* __restrict__ rposh,
                                              const float* __restrict__ rposw,
                                              u16* __restrict__ Xb, u16* __restrict__ W1T,
                                              u16* __restrict__ PT,
                                              u16* __restrict__ rh8, u16* __restrict__ rw8){
  __shared__ float tile[64*65];
  const int b = blockIdx.x, t = threadIdx.x;
  if (b < 1536){
    int i = b*256 + t;
    const float4* p = (const float4*)X32;
    float4 a = p[i*2], c = p[i*2+1];
    ushort8 o;
    o[0]=f2bf(a.x); o[1]=f2bf(a.y); o[2]=f2bf(a.z); o[3]=f2bf(a.w);
    o[4]=f2bf(c.x); o[5]=f2bf(c.y); o[6]=f2bf(c.z); o[7]=f2bf(c.w);
    ((ushort8*)Xb)[i] = o;
  } else if (b < 1968){
    int bb = b - 1536;
    tr_body(qkvw, W1T, 768, 2304, bb % 12, bb / 12, t, tile);
  } else if (b < 2112){
    int bb = b - 1968;
    tr_body(projw, PT, 768, 768, bb % 12, bb / 12, t, tile);
  } else {
    int i = (b - 2112)*256 + t;          // [0,16384)
    if (i < 8192)      rh8[i] = f2bf(i < 8128 ? rposh[i]*8.0f : 0.0f);
    else { int j = i - 8192; rw8[j] = f2bf(j < 8128 ? rposw[j]*8.0f : 0.0f); }
  }
}

// ---------------- QKV GEMM: (4096x768)x(768x2304), split to Qs/Kf/Vf ----------------
// K fragment-linear:  Kf[h][kb][f=ct*2+ks][lane=lg*16+lr][e] = K[kb*64+ct*16+lr][ks*32+lg*8+e]
// V fragment-linear with PERMUTED k (pi(lg,e) = (e>>2)*16 + lg*4 + (e&3)) so the
// flash PV B-operand can be assembled IN-REGISTER from the swapped-QK^T output.

__global__ __launch_bounds__(256) void k_qkv(const u16* __restrict__ X, const u16* __restrict__ WT,
                                             const float* __restrict__ bias,
                                             u16* __restrict__ Qs, u16* __restrict__ Kf, u16* __restrict__ Vf){
  __shared__ __align__(16) u16 At[128*64];
  __shared__ __align__(16) u16 Bt[128*64];
  __shared__ __align__(16) u16 Tt[4][64*72];   // per-wave repack tile, pad 72 keeps 16B align
  const int tid = threadIdx.x, lane = tid & 63, w = tid >> 6;
  const int m0 = blockIdx.x*128, n0 = blockIdx.y*128;
  const int wr = (w >> 1)*64, wc = (w & 1)*64;
  const int lr = lane & 15, lg = lane >> 4;
  const int srcRow = w*32 + (lane >> 3);
  const int srcK   = (lane & 7)*8;
  f32x4 acc[4][4] = {};
  for (int kt = 0; kt < 12; ++kt){
    const int kbase = kt*64;
    for (int s = 0; s < 4; ++s){
      gload16(X  + (size_t)(m0 + srcRow + s*8)*768 + kbase + srcK, At + (w*32 + s*8)*64);
      gload16(WT + (size_t)(n0 + srcRow + s*8)*768 + kbase + srcK, Bt + (w*32 + s*8)*64);
    }
    __syncthreads();
    bf16x8 af[2][4], bfr[2][4];
    for (int ks = 0; ks < 2; ++ks)
      for (int i = 0; i < 4; ++i){
        af[ks][i]  = ld8(At + (wr + i*16 + lr)*64 + ks*32 + lg*8);
        bfr[ks][i] = ld8(Bt + (wc + i*16 + lr)*64 + ks*32 + lg*8);
      }
    for (int ks = 0; ks < 2; ++ks)
      for (int mi = 0; mi < 4; ++mi)
        for (int ni = 0; ni < 4; ++ni)
          acc[mi][ni] = MFMA(af[ks][mi], bfr[ks][ni], acc[mi][ni], 0, 0, 0);
    __syncthreads();
  }
  const int colbase = n0 + wc;            // 64-aligned -> s3/hh uniform per wave
  const int s3 = colbase / 768;
  const int hh = (colbase % 768) >> 6;
  const int rowbase = m0 + wr;            // 64-aligned -> kb uniform per wave
  if (s3 == 0){
    for (int mi = 0; mi < 4; ++mi)
      for (int ni = 0; ni < 4; ++ni){
        float bv = bias[colbase + ni*16 + lr];
        for (int r = 0; r < 4; ++r){
          int row = rowbase + mi*16 + lg*4 + r;
          // Q pre-scaled by head_dim^-0.5 * log2(e) so softmax runs in exp2 domain
          Qs[((size_t)hh*4096 + row)*64 + ni*16 + lr] =
              f2bf((acc[mi][ni][r] + bv)*(0.125f*1.44269504f));
        }
      }
  } else {
    u16* T = Tt[w];
    for (int mi = 0; mi < 4; ++mi)
      for (int ni = 0; ni < 4; ++ni){
        float bv = bias[colbase + ni*16 + lr];
        for (int r = 0; r < 4; ++r){
          int row_l = mi*16 + lg*4 + r, col_l = ni*16 + lr;
          u16 v = f2bf(acc[mi][ni][r] + bv);
          if (s3 == 1) T[row_l*72 + col_l] = v;     // K: [token][d]
          else         T[col_l*72 + row_l] = v;     // V: [d][token] (transposed)
        }
      }
    // same-wave LDS write->read; no cross-wave sharing, compiler inserts lgkmcnt
    const int kb = rowbase >> 6;
    u16* dst = (s3 == 1 ? Kf : Vf) + ((size_t)hh*64 + kb)*4096 + lane*8;
    if (s3 == 1){
      #pragma unroll
      for (int f = 0; f < 8; ++f){
        int a = f >> 1, ks = f & 1;
        *(ushort8*)&dst[f*512] = *(const ushort8*)&T[(a*16 + lr)*72 + ks*32 + lg*8];
      }
    } else {
      // permuted-k V fragments: elems 0-3 <- tokens ks*32+lg*4+(0..3),
      //                         elems 4-7 <- tokens ks*32+16+lg*4+(0..3)
      #pragma unroll
      for (int f = 0; f < 8; ++f){
        int a = f >> 1, ks = f & 1;
        const int rowb = (a*16 + lr)*72 + ks*32 + lg*4;
        ushort4v lo = *(const ushort4v*)&T[rowb];
        ushort4v hi = *(const ushort4v*)&T[rowb + 16];
        ushort8 o;
        o[0]=lo[0]; o[1]=lo[1]; o[2]=lo[2]; o[3]=lo[3];
        o[4]=hi[0]; o[5]=hi[1]; o[6]=hi[2]; o[7]=hi[3];
        *(ushort8*)&dst[f*512] = o;
      }
    }
  }
}

// ---------------- rel_h / rel_w via MFMA; grid (64 qh, 12 h) ----------------

__global__ __launch_bounds__(256) void k_rel(const u16* __restrict__ Qs, const u16* __restrict__ Rh8,
                                             const u16* __restrict__ Rw8,
                                             u16* __restrict__ relh, u16* __restrict__ relw){
  __shared__ __align__(16) u16 Ql[64*64];
  __shared__ __align__(16) u16 Rhl[64*64];
  __shared__ __align__(16) u16 Rwl[128*64];
  const int tid = threadIdx.x, lane = tid & 63, w = tid >> 6;
  const int qh = blockIdx.x, h = blockIdx.y;
  const int lr = lane & 15, lg = lane >> 4;
  for (int j = 0; j < 2; ++j){
    int ch = tid + 256*j;             // 0..511
    int row = ch >> 3, k8 = (ch & 7)*8;
    *(ushort8*)&Ql[row*64 + k8]  = *(const ushort8*)&Qs[((size_t)h*4096 + qh*64 + row)*64 + k8];
    *(ushort8*)&Rhl[row*64 + k8] = *(const ushort8*)&Rh8[(qh + row)*64 + k8];
  }
  for (int j = 0; j < 4; ++j){
    int ch = tid + 256*j;             // 0..1023
    int row = ch >> 3, k8 = (ch & 7)*8;
    *(ushort8*)&Rwl[row*64 + k8] = *(const ushort8*)&Rw8[row*64 + k8];
  }
  __syncthreads();
  bf16x8 a[2];
  for (int ks = 0; ks < 2; ++ks) a[ks] = ld8(Ql + (w*16 + lr)*64 + ks*32 + lg*8);
  // rel_h[qw][kh] = (Q . rel_pos_h[qh+63-kh]) ; computed as Q @ Rh[qh+c]^T, kh = 63-c
  for (int ct = 0; ct < 4; ++ct){
    f32x4 c = {};
    for (int ks = 0; ks < 2; ++ks)
      c = MFMA(a[ks], ld8(Rhl + (ct*16 + lr)*64 + ks*32 + lg*8), c, 0, 0, 0);
    int kh = 63 - (ct*16 + lr);
    for (int r = 0; r < 4; ++r){
      int qw = w*16 + lg*4 + r;
      relh[((size_t)h*4096 + qh*64 + qw)*64 + kh] = f2bf(c[r]);
    }
  }
  // rel_w[qw][kw] = (Q . rel_pos_w[qw+63-kw]) ; full band, keep valid kw
  for (int ct = 0; ct < 8; ++ct){
    f32x4 c = {};
    for (int ks = 0; ks < 2; ++ks)
      c = MFMA(a[ks], ld8(Rwl + (ct*16 + lr)*64 + ks*32 + lg*8), c, 0, 0, 0);
    int cc = ct*16 + lr;
    for (int r = 0; r < 4; ++r){
      int qw = w*16 + lg*4 + r;
      int kw = qw + 63 - cc;
      if (kw >= 0 && kw < 64)
        relw[((size_t)h*4096 + qh*64 + qw)*64 + kw] = f2bf(c[r]);
    }
  }
}

// ---------------- flash attention; flat grid 768, 4 waves ----------------
// R17 = R14 proven body (scalar lazy softmax, in-register P via permuted-k Vf)
// + T4 counted-vmcnt pipeline: __syncthreads drains vmcnt(0) (kills the
// 2-deep prefetch); replaced with asm s_waitcnt vmcnt(4) + raw s_barrier.
// FIFO retirement: <=4 outstanding => the current tile's 4 stage loads (the
// oldest) completed; compiler-issued extra VMEM (rhbase) only makes the wait
// more conservative. Last iteration peeled with vmcnt(0). sched_barrier(0)
// after each wait/barrier pins MFMA/ds_read ordering (rule #18).
// Head->XCD affinity (768 = 8*96): <=2 heads (2MB KV) per XCD L2.
// launch_bounds(256,3): arch-VGPR budget ~84; spill tripwire = FETCH_SIZE.

__global__ __launch_bounds__(256, 3) void k_flash(const u16* __restrict__ Qs, const u16* __restrict__ Kf,
                                                  const u16* __restrict__ Vf,
                                                  const u16* __restrict__ relh, const u16* __restrict__ relw,
                                                  u16* __restrict__ Ob){
  __shared__ __align__(16) u16 Kl[2][4096];       // 8KB per K tile (fragment-linear copy)
  __shared__ __align__(16) u16 Vl[2][4096];       // 8KB per V tile (permuted-k layout)
  const int tid = threadIdx.x, lane = tid & 63, w = tid >> 6;
  const int b = blockIdx.x;
  const int p = (b & 7)*96 + (b >> 3);         // head->XCD affinity remap (768 = 8*96)
  const int h = p >> 6, qb = p & 63;
  const int lr = lane & 15, lg = lane >> 4;
  const size_t hq = (size_t)h*4096;
  const int q = qb*64 + w*16 + lr;             // this lane's q row (S^T column)

  const bf16x8 qf0 = ld8(Qs + (hq + q)*64 + lg*8);
  const bf16x8 qf1 = ld8(Qs + (hq + q)*64 + 32 + lg*8);
  // rel_w bias row unpacked to f32 once
  float rwf[4][4];
  #pragma unroll
  for (int ct = 0; ct < 4; ++ct){
    ushort4v t = *(const ushort4v*)&relw[(hq + q)*64 + ct*16 + lg*4];
    #pragma unroll
    for (int r = 0; r < 4; ++r) rwf[ct][r] = bf2f(t[r]);
  }

  const u16* KfH = Kf + (size_t)h*262144;      // + kb*4096
  const u16* VfH = Vf + (size_t)h*262144;
  const u16* rhbase = relh + (hq + q)*64;

  float m = -1e30f, lsum = 0.f;                // lsum per-lane partial (reduced at end)
  f32x4 oacc[4] = {};                          // O^T: rows d = dt*16+lg*4+r, col q = lr

  // wave w stages 1KB chunks {2w, 2w+1} of K and V (8 chunks each, 4 waves).
  auto stage = [&](int buf, int kb){
    const u16* ks = KfH + kb*4096 + w*1024 + lane*8;
    const u16* vs = VfH + kb*4096 + w*1024 + lane*8;
    gload16(ks,       &Kl[buf][w*1024]);
    gload16(ks + 512, &Kl[buf][w*1024 + 512]);
    gload16(vs,       &Vl[buf][w*1024]);
    gload16(vs + 512, &Vl[buf][w*1024 + 512]);
  };

#define ITERBODY(KB, BUF)                                                     \
  {                                                                           \
    const u16* KL = Kl[BUF] + lane*8;                                         \
    const u16* VL = Vl[BUF] + lane*8;                                         \
    const float rhv = bf2f(rhbase[KB]);                                       \
    f32x4 s[4];                                                               \
    _Pragma("unroll")                                                         \
    for (int ct = 0; ct < 4; ++ct){                                           \
      _Pragma("unroll")                                                       \
      for (int r = 0; r < 4; ++r) s[ct][r] = rhv + rwf[ct][r];                \
    }                                                                         \
    __builtin_amdgcn_s_setprio(1);                                            \
    _Pragma("unroll")                                                         \
    for (int ct = 0; ct < 4; ++ct){                                           \
      s[ct] = MFMA(ld8(KL + (ct*2)*512),   qf0, s[ct], 0, 0, 0);              \
      s[ct] = MFMA(ld8(KL + (ct*2+1)*512), qf1, s[ct], 0, 0, 0);              \
    }                                                                         \
    __builtin_amdgcn_s_setprio(0);                                            \
    /* lane-local max over own 16 values */                                   \
    float pm0 = fmaxf(fmaxf(s[0][0], s[0][1]), fmaxf(fmaxf(s[0][2], s[0][3]), \
                      fmaxf(s[1][0], s[1][1])));                              \
    float pm1 = fmaxf(fmaxf(s[1][2], s[1][3]), fmaxf(fmaxf(s[2][0], s[2][1]), \
                      fmaxf(s[2][2], s[2][3])));                              \
    float pm2 = fmaxf(fmaxf(s[3][0], s[3][1]), fmaxf(s[3][2], s[3][3]));      \
    float pm = fmaxf(fmaxf(pm0, pm1), pm2);                                   \
    /* lazy rescale: cross-lane reduce only when some row max grew */         \
    if (__any(pm > m)){                                                       \
      pm = fmaxf(pm, __shfl_xor(pm, 16, 64));                                 \
      pm = fmaxf(pm, __shfl_xor(pm, 32, 64));                                 \
      const float nm = fmaxf(m, pm);                                          \
      const float corr = EXP2(m - nm);                                        \
      m = nm;                                                                 \
      lsum *= corr;                                                           \
      _Pragma("unroll")                                                       \
      for (int dt = 0; dt < 4; ++dt)                                          \
        _Pragma("unroll")                                                     \
        for (int r = 0; r < 4; ++r) oacc[dt][r] *= corr;                      \
    }                                                                         \
    float rs = 0.f;                                                           \
    _Pragma("unroll")                                                         \
    for (int ct = 0; ct < 4; ++ct){                                           \
      _Pragma("unroll")                                                       \
      for (int r = 0; r < 4; ++r){                                            \
        float p2 = EXP2(s[ct][r] - m);                                        \
        s[ct][r] = p2; rs += p2;                                              \
      }                                                                       \
    }                                                                         \
    lsum += rs;   /* per-lane partial; no shfl here */                        \
    /* P^T B-fragments in-register (k-permuted to match Vf layout) */         \
    uint4v u0, u1;                                                            \
    u0[0] = cvtpk(s[0][0], s[0][1]); u0[1] = cvtpk(s[0][2], s[0][3]);         \
    u0[2] = cvtpk(s[1][0], s[1][1]); u0[3] = cvtpk(s[1][2], s[1][3]);         \
    u1[0] = cvtpk(s[2][0], s[2][1]); u1[1] = cvtpk(s[2][2], s[2][3]);         \
    u1[2] = cvtpk(s[3][0], s[3][1]); u1[3] = cvtpk(s[3][2], s[3][3]);         \
    bf16x8 pa0 = __builtin_bit_cast(bf16x8, u0);                              \
    bf16x8 pa1 = __builtin_bit_cast(bf16x8, u1);                              \
    __builtin_amdgcn_s_setprio(1);                                            \
    _Pragma("unroll")                                                         \
    for (int dt = 0; dt < 4; ++dt){                                           \
      oacc[dt] = MFMA(ld8(VL + (dt*2)*512),   pa0, oacc[dt], 0, 0, 0);        \
      oacc[dt] = MFMA(ld8(VL + (dt*2+1)*512), pa1, oacc[dt], 0, 0, 0);        \
    }                                                                         \
    __builtin_amdgcn_s_setprio(0);                                            \
  }

  stage(0, 0);
  stage(1, 1);                         // prefetch depth 2: 8 outstanding/wave
  for (int t = 0; t < 63; ++t){
    asm volatile("s_waitcnt vmcnt(4)" ::: "memory");   // tile t's 4 loads done
    __builtin_amdgcn_s_barrier();
    __builtin_amdgcn_sched_barrier(0);
    ITERBODY(t, (t & 1))
    __builtin_amdgcn_s_barrier();      // all waves done reading buf (t&1)
    __builtin_amdgcn_sched_barrier(0);
    if (t < 62) stage(t & 1, t + 2);   // refill behind the pipeline
  }
  asm volatile("s_waitcnt vmcnt(0)" ::: "memory");
  __builtin_amdgcn_s_barrier();
  __builtin_amdgcn_sched_barrier(0);
  ITERBODY(63, 1)
#undef ITERBODY

  // epilogue: single cross-lane sum reduce of the per-lane lsum partials
  lsum += __shfl_xor(lsum, 16, 64);
  lsum += __shfl_xor(lsum, 32, 64);
  const float inv = 1.0f / lsum;
  #pragma unroll
  for (int dt = 0; dt < 4; ++dt){
    ushort4v pk;
    #pragma unroll
    for (int r = 0; r < 4; ++r) pk[r] = f2bf(oacc[dt][r]*inv);
    *(ushort4v*)&Ob[(size_t)q*768 + h*64 + dt*16 + lg*4] = pk;
  }
}

// ---------------- proj GEMM: (4096x768)x(768x768) + b -> f32 out ----------------

__global__ __launch_bounds__(256) void k_proj(const u16* __restrict__ A, const u16* __restrict__ WT,
                                              const float* __restrict__ bias, float* __restrict__ out){
  __shared__ __align__(16) u16 At[128*64];
  __shared__ __align__(16) u16 Bt[128*64];
  const int tid = threadIdx.x, lane = tid & 63, w = tid >> 6;
  const int m0 = blockIdx.x*128, n0 = blockIdx.y*128;
  const int wr = (w >> 1)*64, wc = (w & 1)*64;
  const int lr = lane & 15, lg = lane >> 4;
  const int srcRow = w*32 + (lane >> 3);
  const int srcK   = (lane & 7)*8;
  f32x4 acc[4][4] = {};
  for (int kt = 0; kt < 12; ++kt){
    const int kbase = kt*64;
    for (int s = 0; s < 4; ++s){
      gload16(A  + (size_t)(m0 + srcRow + s*8)*768 + kbase + srcK, At + (w*32 + s*8)*64);
      gload16(WT + (size_t)(n0 + srcRow + s*8)*768 + kbase + srcK, Bt + (w*32 + s*8)*64);
    }
    __syncthreads();
    bf16x8 af[2][4], bfr[2][4];
    for (int ks = 0; ks < 2; ++ks)
      for (int i = 0; i < 4; ++i){
        af[ks][i]  = ld8(At + (wr + i*16 + lr)*64 + ks*32 + lg*8);
        bfr[ks][i] = ld8(Bt + (wc + i*16 + lr)*64 + ks*32 + lg*8);
      }
    for (int ks = 0; ks < 2; ++ks)
      for (int mi = 0; mi < 4; ++mi)
        for (int ni = 0; ni < 4; ++ni)
          acc[mi][ni] = MFMA(af[ks][mi], bfr[ks][ni], acc[mi][ni], 0, 0, 0);
    __syncthreads();
  }
  for (int mi = 0; mi < 4; ++mi)
    for (int ni = 0; ni < 4; ++ni){
      int col = n0 + wc + ni*16 + lr;
      float bv = bias[col];
      for (int r = 0; r < 4; ++r){
        int row = m0 + wr + mi*16 + lg*4 + r;
        out[(size_t)row*768 + col] = acc[mi][ni][r] + bv;
      }
    }
}

// ---------------- launch ----------------

extern "C" void kernel_launch(void* const* d_in, const int* in_sizes, int n_in,
                              void* d_out, int out_size, void* d_ws, size_t ws_size,
                              hipStream_t stream){
  const float* X32   = (const float*)d_in[0];
  const float* qkvw  = (const float*)d_in[1];
  const float* qkvb  = (const float*)d_in[2];
  const float* projw = (const float*)d_in[3];
  const float* projb = (const float*)d_in[4];
  const float* rposh = (const float*)d_in[5];
  const float* rposw = (const float*)d_in[6];

  u16* Xb  = (u16*)d_ws;            // 4096*768
  u16* W1T = Xb  + 3145728;         // 2304*768
  u16* PT  = W1T + 1769472;         // 768*768
  u16* Rh8 = PT  + 589824;          // 128*64 (padded)
  u16* Rw8 = Rh8 + 8192;            // 128*64 (padded)
  u16* Qs  = Rw8 + 8192;            // 12*4096*64 (pre-scaled by 1/8 * log2e)
  u16* Kf  = Qs  + 3145728;         // fragment-linear K [12][64][8][64][8]
  u16* Vf  = Kf  + 3145728;         // fragment-linear V^T, k-permuted [12][64][8][64][8]
  u16* Rlh = Vf  + 3145728;         // [12][4096][64]
  u16* Rlw = Rlh + 3145728;         // [12][4096][64]
  u16* Ob  = Rlw + 3145728;         // [4096][768]
  float* out = (float*)d_out;

  k_prep <<<2176, 256, 0, stream>>>(X32, qkvw, projw, rposh, rposw, Xb, W1T, PT, Rh8, Rw8);
  k_qkv  <<<dim3(32, 18), 256, 0, stream>>>(Xb, W1T, qkvb, Qs, Kf, Vf);
  k_rel  <<<dim3(64, 12), 256, 0, stream>>>(Qs, Rh8, Rw8, Rlh, Rlw);
  k_flash<<<768, 256, 0, stream>>>(Qs, Kf, Vf, Rlh, Rlw, Ob);
  k_proj <<<dim3(32, 6), 256, 0, stream>>>(Ob, PT, projb, out);
}

// Round 20
// 156.410 us; speedup vs baseline: 1.0533x; 1.0516x over previous
//
#include <hip/hip_runtime.h>
#include <stdint.h>

typedef unsigned short u16;
typedef __bf16 bf16x8 __attribute__((ext_vector_type(8)));
typedef float f32x4 __attribute__((ext_vector_type(4)));
typedef unsigned short ushort8 __attribute__((ext_vector_type(8)));
typedef unsigned short ushort4v __attribute__((ext_vector_type(4)));
typedef uint32_t uint4v __attribute__((ext_vector_type(4)));

#define MFMA __builtin_amdgcn_mfma_f32_16x16x32_bf16
#define EXP2 __builtin_amdgcn_exp2f

__device__ __forceinline__ u16 f2bf(float f){
  uint32_t u = __builtin_bit_cast(uint32_t, f);
  u += 0x7fffu + ((u >> 16) & 1u);
  return (u16)(u >> 16);
}
__device__ __forceinline__ float bf2f(u16 h){
  uint32_t u = ((uint32_t)h) << 16;
  return __builtin_bit_cast(float, u);
}
__device__ __forceinline__ uint32_t cvtpk(float lo, float hi){
  uint32_t r;
  asm("v_cvt_pk_bf16_f32 %0, %1, %2" : "=v"(r) : "v"(lo), "v"(hi));
  return r;
}
__device__ __forceinline__ bf16x8 ld8(const u16* p){
  return __builtin_bit_cast(bf16x8, *(const ushort8*)p);
}
__device__ __forceinline__ void gload16(const void* g, void* l){
  __builtin_amdgcn_global_load_lds((__attribute__((address_space(1))) void*)(void*)g,
                                   (__attribute__((address_space(3))) void*)l, 16, 0, 0);
}

// ---------------- fused preprocessing: conv8 | tr(qkv_w) | tr(proj_w) | relconv ----------------

__device__ __forceinline__ void tr_body(const float* __restrict__ in, u16* __restrict__ out,
                                        int R, int Cc, int bx, int by, int t, float* tile /*64x65*/){
  int r0 = bx*64, c0 = by*64;
  int c = t & 63, r4 = t >> 6;
  for (int i = 0; i < 16; ++i)
    tile[(r4 + i*4)*65 + c] = in[(size_t)(r0 + r4 + i*4)*Cc + c0 + c];
  __syncthreads();
  for (int i = 0; i < 16; ++i){
    int rr = r4 + i*4;
    out[(size_t)(c0 + rr)*R + r0 + c] = f2bf(tile[c*65 + rr]);
  }
}

__global__ __launch_bounds__(256) void k_prep(const float* __restrict__ X32,
                                              const float* __restrict__ qkvw,
                                              const float* __restrict__ projw,
                                              const float* __restrict__ rposh,
                                              const float* __restrict__ rposw,
                                              u16* __restrict__ Xb, u16* __restrict__ W1T,
                                              u16* __restrict__ PT,
                                              u16* __restrict__ rh8, u16* __restrict__ rw8){
  __shared__ float tile[64*65];
  const int b = blockIdx.x, t = threadIdx.x;
  if (b < 1536){
    int i = b*256 + t;
    const float4* p = (const float4*)X32;
    float4 a = p[i*2], c = p[i*2+1];
    ushort8 o;
    o[0]=f2bf(a.x); o[1]=f2bf(a.y); o[2]=f2bf(a.z); o[3]=f2bf(a.w);
    o[4]=f2bf(c.x); o[5]=f2bf(c.y); o[6]=f2bf(c.z); o[7]=f2bf(c.w);
    ((ushort8*)Xb)[i] = o;
  } else if (b < 1968){
    int bb = b - 1536;
    tr_body(qkvw, W1T, 768, 2304, bb % 12, bb / 12, t, tile);
  } else if (b < 2112){
    int bb = b - 1968;
    tr_body(projw, PT, 768, 768, bb % 12, bb / 12, t, tile);
  } else {
    int i = (b - 2112)*256 + t;          // [0,16384)
    if (i < 8192)      rh8[i] = f2bf(i < 8128 ? rposh[i]*8.0f : 0.0f);
    else { int j = i - 8192; rw8[j] = f2bf(j < 8128 ? rposw[j]*8.0f : 0.0f); }
  }
}

// ---------------- QKV GEMM: (4096x768)x(768x2304), split to Qs/Kf/Vf ----------------
// K fragment-linear:  Kf[h][kb][f=ct*2+ks][lane=lg*16+lr][e] = K[kb*64+ct*16+lr][ks*32+lg*8+e]
// V fragment-linear with PERMUTED k (pi(lg,e) = (e>>2)*16 + lg*4 + (e&3)) so the
// flash PV B-operand can be assembled IN-REGISTER from the swapped-QK^T output.

__global__ __launch_bounds__(256) void k_qkv(const u16* __restrict__ X, const u16* __restrict__ WT,
                                             const float* __restrict__ bias,
                                             u16* __restrict__ Qs, u16* __restrict__ Kf, u16* __restrict__ Vf){
  __shared__ __align__(16) u16 At[128*64];
  __shared__ __align__(16) u16 Bt[128*64];
  __shared__ __align__(16) u16 Tt[4][64*72];   // per-wave repack tile, pad 72 keeps 16B align
  const int tid = threadIdx.x, lane = tid & 63, w = tid >> 6;
  const int m0 = blockIdx.x*128, n0 = blockIdx.y*128;
  const int wr = (w >> 1)*64, wc = (w & 1)*64;
  const int lr = lane & 15, lg = lane >> 4;
  const int srcRow = w*32 + (lane >> 3);
  const int srcK   = (lane & 7)*8;
  f32x4 acc[4][4] = {};
  for (int kt = 0; kt < 12; ++kt){
    const int kbase = kt*64;
    for (int s = 0; s < 4; ++s){
      gload16(X  + (size_t)(m0 + srcRow + s*8)*768 + kbase + srcK, At + (w*32 + s*8)*64);
      gload16(WT + (size_t)(n0 + srcRow + s*8)*768 + kbase + srcK, Bt + (w*32 + s*8)*64);
    }
    __syncthreads();
    bf16x8 af[2][4], bfr[2][4];
    for (int ks = 0; ks < 2; ++ks)
      for (int i = 0; i < 4; ++i){
        af[ks][i]  = ld8(At + (wr + i*16 + lr)*64 + ks*32 + lg*8);
        bfr[ks][i] = ld8(Bt + (wc + i*16 + lr)*64 + ks*32 + lg*8);
      }
    for (int ks = 0; ks < 2; ++ks)
      for (int mi = 0; mi < 4; ++mi)
        for (int ni = 0; ni < 4; ++ni)
          acc[mi][ni] = MFMA(af[ks][mi], bfr[ks][ni], acc[mi][ni], 0, 0, 0);
    __syncthreads();
  }
  const int colbase = n0 + wc;            // 64-aligned -> s3/hh uniform per wave
  const int s3 = colbase / 768;
  const int hh = (colbase % 768) >> 6;
  const int rowbase = m0 + wr;            // 64-aligned -> kb uniform per wave
  if (s3 == 0){
    for (int mi = 0; mi < 4; ++mi)
      for (int ni = 0; ni < 4; ++ni){
        float bv = bias[colbase + ni*16 + lr];
        for (int r = 0; r < 4; ++r){
          int row = rowbase + mi*16 + lg*4 + r;
          // Q pre-scaled by head_dim^-0.5 * log2(e) so softmax runs in exp2 domain
          Qs[((size_t)hh*4096 + row)*64 + ni*16 + lr] =
              f2bf((acc[mi][ni][r] + bv)*(0.125f*1.44269504f));
        }
      }
  } else {
    u16* T = Tt[w];
    for (int mi = 0; mi < 4; ++mi)
      for (int ni = 0; ni < 4; ++ni){
        float bv = bias[colbase + ni*16 + lr];
        for (int r = 0; r < 4; ++r){
          int row_l = mi*16 + lg*4 + r, col_l = ni*16 + lr;
          u16 v = f2bf(acc[mi][ni][r] + bv);
          if (s3 == 1) T[row_l*72 + col_l] = v;     // K: [token][d]
          else         T[col_l*72 + row_l] = v;     // V: [d][token] (transposed)
        }
      }
    // same-wave LDS write->read; no cross-wave sharing, compiler inserts lgkmcnt
    const int kb = rowbase >> 6;
    u16* dst = (s3 == 1 ? Kf : Vf) + ((size_t)hh*64 + kb)*4096 + lane*8;
    if (s3 == 1){
      #pragma unroll
      for (int f = 0; f < 8; ++f){
        int a = f >> 1, ks = f & 1;
        *(ushort8*)&dst[f*512] = *(const ushort8*)&T[(a*16 + lr)*72 + ks*32 + lg*8];
      }
    } else {
      // permuted-k V fragments: elems 0-3 <- tokens ks*32+lg*4+(0..3),
      //                         elems 4-7 <- tokens ks*32+16+lg*4+(0..3)
      #pragma unroll
      for (int f = 0; f < 8; ++f){
        int a = f >> 1, ks = f & 1;
        const int rowb = (a*16 + lr)*72 + ks*32 + lg*4;
        ushort4v lo = *(const ushort4v*)&T[rowb];
        ushort4v hi = *(const ushort4v*)&T[rowb + 16];
        ushort8 o;
        o[0]=lo[0]; o[1]=lo[1]; o[2]=lo[2]; o[3]=lo[3];
        o[4]=hi[0]; o[5]=hi[1]; o[6]=hi[2]; o[7]=hi[3];
        *(ushort8*)&dst[f*512] = o;
      }
    }
  }
}

// ---------------- flash attention + fused rel bias; flat grid 768, 4 waves ----------------
// R20 = R14 proven loop (K+V LDS-staged dbuf, __syncthreads, scalar lazy softmax,
// in-register P via permuted-k Vf) + k_rel FUSED into the block prologue:
// block = (h, qh) — the same unit k_rel used. Swapped-operand MFMAs give each
// lane rel_h[own q][16 kh] (A rows = Rh8[qh+63-kh]) and the rel_w band
// (A rows = Rw8[c], keep kw = qw+63-c in [0,64); c spans [0,128) exactly once
// across (ct2,lg,r)). Results stored to per-wave LDS (bf16, stride 68 ->
// conflict-free scalar reads), read exactly where R14 read global relh/relw.
// f2bf->bf2f roundtrip preserved -> numerics identical to k_rel.
// Kills the k_rel launch (~10us) + 24MB Rlh/Rlw global roundtrip.
// Head->XCD affinity (768 = 8*96): <=2 heads (2MB KV) per XCD L2.
// launch_bounds(256,3): arch-VGPR budget ~84; spill tripwire = FETCH_SIZE.

__global__ __launch_bounds__(256, 3) void k_flash(const u16* __restrict__ Qs, const u16* __restrict__ Kf,
                                                  const u16* __restrict__ Vf,
                                                  const u16* __restrict__ Rh8, const u16* __restrict__ Rw8,
                                                  u16* __restrict__ Ob){
  __shared__ __align__(16) u16 Kl[2][4096];       // 8KB per K tile (fragment-linear copy)
  __shared__ __align__(16) u16 Vl[2][4096];       // 8KB per V tile (permuted-k layout)
  __shared__ __align__(16) u16 RhL[4][16*68];     // per-wave rel_h[q][kh], pad 68
  __shared__ __align__(16) u16 RwL[4][16*68];     // per-wave rel_w[q][kw], pad 68
  const int tid = threadIdx.x, lane = tid & 63, w = tid >> 6;
  const int b = blockIdx.x;
  const int p = (b & 7)*96 + (b >> 3);         // head->XCD affinity remap (768 = 8*96)
  const int h = p >> 6, qb = p & 63;           // qb == image row qh
  const int lr = lane & 15, lg = lane >> 4;
  const size_t hq = (size_t)h*4096;
  const int q = qb*64 + w*16 + lr;             // this lane's q row (S^T column)

  const u16* KfH = Kf + (size_t)h*262144;      // + kb*4096
  const u16* VfH = Vf + (size_t)h*262144;

  // wave w stages 1KB chunks {2w, 2w+1} of K and V (8 chunks each, 4 waves).
  auto stage = [&](int buf, int kb){
    const u16* ks = KfH + kb*4096 + w*1024 + lane*8;
    const u16* vs = VfH + kb*4096 + w*1024 + lane*8;
    gload16(ks,       &Kl[buf][w*1024]);
    gload16(ks + 512, &Kl[buf][w*1024 + 512]);
    gload16(vs,       &Vl[buf][w*1024]);
    gload16(vs + 512, &Vl[buf][w*1024 + 512]);
  };

  stage(0, 0);                                 // start tile-0 DMA; prologue overlaps it

  const bf16x8 qf0 = ld8(Qs + (hq + q)*64 + lg*8);
  const bf16x8 qf1 = ld8(Qs + (hq + q)*64 + 32 + lg*8);

  // ---- fused rel_h: lane ends with rel_h[own q][kh=ct*16+lg*4+r] ----
  u16* RhLw = RhL[w];
  #pragma unroll
  for (int ct = 0; ct < 4; ++ct){
    f32x4 c = {};
    const u16* r0 = Rh8 + (qb + 63 - (ct*16 + lr))*64 + lg*8;
    c = MFMA(ld8(r0),      qf0, c, 0, 0, 0);
    c = MFMA(ld8(r0 + 32), qf1, c, 0, 0, 0);
    #pragma unroll
    for (int r = 0; r < 4; ++r)
      RhLw[lr*68 + ct*16 + lg*4 + r] = f2bf(c[r]);
  }
  // ---- fused rel_w band: lane holds out[c=ct2*16+lg*4+r][own q]; keep kw in [0,64) ----
  u16* RwLw = RwL[w];
  #pragma unroll
  for (int ct2 = 0; ct2 < 8; ++ct2){
    f32x4 c = {};
    const u16* r0 = Rw8 + (ct2*16 + lr)*64 + lg*8;
    c = MFMA(ld8(r0),      qf0, c, 0, 0, 0);
    c = MFMA(ld8(r0 + 32), qf1, c, 0, 0, 0);
    #pragma unroll
    for (int r = 0; r < 4; ++r){
      int kw = (w*16 + lr) + 63 - (ct2*16 + lg*4 + r);
      if (kw >= 0 && kw < 64) RwLw[lr*68 + kw] = f2bf(c[r]);
    }
  }
  // rel_w bias row unpacked to f32 once (same-wave LDS write->read, lgkmcnt by compiler)
  float rwf[4][4];
  #pragma unroll
  for (int ct = 0; ct < 4; ++ct){
    ushort4v t = *(const ushort4v*)&RwLw[lr*68 + ct*16 + lg*4];
    #pragma unroll
    for (int r = 0; r < 4; ++r) rwf[ct][r] = bf2f(t[r]);
  }

  float m = -1e30f, lsum = 0.f;                // lsum per-lane partial (reduced at end)
  f32x4 oacc[4] = {};                          // O^T: rows d = dt*16+lg*4+r, col q = lr

#define ITERBODY(KB, BUF)                                                     \
  {                                                                           \
    const u16* KL = Kl[BUF] + lane*8;                                         \
    const u16* VL = Vl[BUF] + lane*8;                                         \
    const float rhv = bf2f(RhLw[lr*68 + (KB)]);                               \
    f32x4 s[4];                                                               \
    _Pragma("unroll")                                                         \
    for (int ct = 0; ct < 4; ++ct){                                           \
      _Pragma("unroll")                                                       \
      for (int r = 0; r < 4; ++r) s[ct][r] = rhv + rwf[ct][r];                \
    }                                                                         \
    __builtin_amdgcn_s_setprio(1);                                            \
    _Pragma("unroll")                                                         \
    for (int ct = 0; ct < 4; ++ct){                                           \
      s[ct] = MFMA(ld8(KL + (ct*2)*512),   qf0, s[ct], 0, 0, 0);              \
      s[ct] = MFMA(ld8(KL + (ct*2+1)*512), qf1, s[ct], 0, 0, 0);              \
    }                                                                         \
    __builtin_amdgcn_s_setprio(0);                                            \
    /* lane-local max over own 16 values */                                   \
    float pm0 = fmaxf(fmaxf(s[0][0], s[0][1]), fmaxf(fmaxf(s[0][2], s[0][3]), \
                      fmaxf(s[1][0], s[1][1])));                              \
    float pm1 = fmaxf(fmaxf(s[1][2], s[1][3]), fmaxf(fmaxf(s[2][0], s[2][1]), \
                      fmaxf(s[2][2], s[2][3])));                              \
    float pm2 = fmaxf(fmaxf(s[3][0], s[3][1]), fmaxf(s[3][2], s[3][3]));      \
    float pm = fmaxf(fmaxf(pm0, pm1), pm2);                                   \
    /* lazy rescale: cross-lane reduce only when some row max grew */         \
    if (__any(pm > m)){                                                       \
      pm = fmaxf(pm, __shfl_xor(pm, 16, 64));                                 \
      pm = fmaxf(pm, __shfl_xor(pm, 32, 64));                                 \
      const float nm = fmaxf(m, pm);                                          \
      const float corr = EXP2(m - nm);                                        \
      m = nm;                                                                 \
      lsum *= corr;                                                           \
      _Pragma("unroll")                                                       \
      for (int dt = 0; dt < 4; ++dt)                                          \
        _Pragma("unroll")                                                     \
        for (int r = 0; r < 4; ++r) oacc[dt][r] *= corr;                      \
    }                                                                         \
    float rs = 0.f;                                                           \
    _Pragma("unroll")                                                         \
    for (int ct = 0; ct < 4; ++ct){                                           \
      _Pragma("unroll")                                                       \
      for (int r = 0; r < 4; ++r){                                            \
        float p2 = EXP2(s[ct][r] - m);                                        \
        s[ct][r] = p2; rs += p2;                                              \
      }                                                                       \
    }                                                                         \
    lsum += rs;   /* per-lane partial; no shfl here */                        \
    /* P^T B-fragments in-register (k-permuted to match Vf layout) */         \
    uint4v u0, u1;                                                            \
    u0[0] = cvtpk(s[0][0], s[0][1]); u0[1] = cvtpk(s[0][2], s[0][3]);         \
    u0[2] = cvtpk(s[1][0], s[1][1]); u0[3] = cvtpk(s[1][2], s[1][3]);         \
    u1[0] = cvtpk(s[2][0], s[2][1]); u1[1] = cvtpk(s[2][2], s[2][3]);         \
    u1[2] = cvtpk(s[3][0], s[3][1]); u1[3] = cvtpk(s[3][2], s[3][3]);         \
    bf16x8 pa0 = __builtin_bit_cast(bf16x8, u0);                              \
    bf16x8 pa1 = __builtin_bit_cast(bf16x8, u1);                              \
    __builtin_amdgcn_s_setprio(1);                                            \
    _Pragma("unroll")                                                         \
    for (int dt = 0; dt < 4; ++dt){                                           \
      oacc[dt] = MFMA(ld8(VL + (dt*2)*512),   pa0, oacc[dt], 0, 0, 0);        \
      oacc[dt] = MFMA(ld8(VL + (dt*2+1)*512), pa1, oacc[dt], 0, 0, 0);        \
    }                                                                         \
    __builtin_amdgcn_s_setprio(0);                                            \
  }

  __syncthreads();                     // drains vmcnt -> tile 0 ready
  for (int kb2 = 0; kb2 < 64; kb2 += 2){
    stage(1, (kb2 + 1) & 63);          // issue next-tile loads (overlap compute)
    ITERBODY(kb2, 0)
    __syncthreads();                   // buf1 staged + all waves done with buf0
    stage(0, (kb2 + 2) & 63);
    ITERBODY(kb2 + 1, 1)
    __syncthreads();
  }
#undef ITERBODY

  // epilogue: single cross-lane sum reduce of the per-lane lsum partials
  lsum += __shfl_xor(lsum, 16, 64);
  lsum += __shfl_xor(lsum, 32, 64);
  const float inv = 1.0f / lsum;
  #pragma unroll
  for (int dt = 0; dt < 4; ++dt){
    ushort4v pk;
    #pragma unroll
    for (int r = 0; r < 4; ++r) pk[r] = f2bf(oacc[dt][r]*inv);
    *(ushort4v*)&Ob[(size_t)q*768 + h*64 + dt*16 + lg*4] = pk;
  }
}

// ---------------- proj GEMM: (4096x768)x(768x768) + b -> f32 out ----------------

__global__ __launch_bounds__(256) void k_proj(const u16* __restrict__ A, const u16* __restrict__ WT,
                                              const float* __restrict__ bias, float* __restrict__ out){
  __shared__ __align__(16) u16 At[128*64];
  __shared__ __align__(16) u16 Bt[128*64];
  const int tid = threadIdx.x, lane = tid & 63, w = tid >> 6;
  const int m0 = blockIdx.x*128, n0 = blockIdx.y*128;
  const int wr = (w >> 1)*64, wc = (w & 1)*64;
  const int lr = lane & 15, lg = lane >> 4;
  const int srcRow = w*32 + (lane >> 3);
  const int srcK   = (lane & 7)*8;
  f32x4 acc[4][4] = {};
  for (int kt = 0; kt < 12; ++kt){
    const int kbase = kt*64;
    for (int s = 0; s < 4; ++s){
      gload16(A  + (size_t)(m0 + srcRow + s*8)*768 + kbase + srcK, At + (w*32 + s*8)*64);
      gload16(WT + (size_t)(n0 + srcRow + s*8)*768 + kbase + srcK, Bt + (w*32 + s*8)*64);
    }
    __syncthreads();
    bf16x8 af[2][4], bfr[2][4];
    for (int ks = 0; ks < 2; ++ks)
      for (int i = 0; i < 4; ++i){
        af[ks][i]  = ld8(At + (wr + i*16 + lr)*64 + ks*32 + lg*8);
        bfr[ks][i] = ld8(Bt + (wc + i*16 + lr)*64 + ks*32 + lg*8);
      }
    for (int ks = 0; ks < 2; ++ks)
      for (int mi = 0; mi < 4; ++mi)
        for (int ni = 0; ni < 4; ++ni)
          acc[mi][ni] = MFMA(af[ks][mi], bfr[ks][ni], acc[mi][ni], 0, 0, 0);
    __syncthreads();
  }
  for (int mi = 0; mi < 4; ++mi)
    for (int ni = 0; ni < 4; ++ni){
      int col = n0 + wc + ni*16 + lr;
      float bv = bias[col];
      for (int r = 0; r < 4; ++r){
        int row = m0 + wr + mi*16 + lg*4 + r;
        out[(size_t)row*768 + col] = acc[mi][ni][r] + bv;
      }
    }
}

// ---------------- launch ----------------

extern "C" void kernel_launch(void* const* d_in, const int* in_sizes, int n_in,
                              void* d_out, int out_size, void* d_ws, size_t ws_size,
                              hipStream_t stream){
  const float* X32   = (const float*)d_in[0];
  const float* qkvw  = (const float*)d_in[1];
  const float* qkvb  = (const float*)d_in[2];
  const float* projw = (const float*)d_in[3];
  const float* projb = (const float*)d_in[4];
  const float* rposh = (const float*)d_in[5];
  const float* rposw = (const float*)d_in[6];

  u16* Xb  = (u16*)d_ws;            // 4096*768
  u16* W1T = Xb  + 3145728;         // 2304*768
  u16* PT  = W1T + 1769472;         // 768*768
  u16* Rh8 = PT  + 589824;          // 128*64 (padded)
  u16* Rw8 = Rh8 + 8192;            // 128*64 (padded)
  u16* Qs  = Rw8 + 8192;            // 12*4096*64 (pre-scaled by 1/8 * log2e)
  u16* Kf  = Qs  + 3145728;         // fragment-linear K [12][64][8][64][8]
  u16* Vf  = Kf  + 3145728;         // fragment-linear V^T, k-permuted [12][64][8][64][8]
  u16* Ob  = Vf  + 3145728;         // [4096][768]
  float* out = (float*)d_out;

  k_prep <<<2176, 256, 0, stream>>>(X32, qkvw, projw, rposh, rposw, Xb, W1T, PT, Rh8, Rw8);
  k_qkv  <<<dim3(32, 18), 256, 0, stream>>>(Xb, W1T, qkvb, Qs, Kf, Vf);
  k_flash<<<768, 256, 0, stream>>>(Qs, Kf, Vf, Rh8, Rw8, Ob);
  k_proj <<<dim3(32, 6), 256, 0, stream>>>(Ob, PT, projb, out);
}

// Round 21
// 152.132 us; speedup vs baseline: 1.0829x; 1.0281x over previous
//
#include <hip/hip_runtime.h>
#include <stdint.h>

typedef unsigned short u16;
typedef __bf16 bf16x8 __attribute__((ext_vector_type(8)));
typedef float f32x4 __attribute__((ext_vector_type(4)));
typedef unsigned short ushort8 __attribute__((ext_vector_type(8)));
typedef unsigned short ushort4v __attribute__((ext_vector_type(4)));
typedef uint32_t uint4v __attribute__((ext_vector_type(4)));

#define MFMA __builtin_amdgcn_mfma_f32_16x16x32_bf16
#define EXP2 __builtin_amdgcn_exp2f

__device__ __forceinline__ u16 f2bf(float f){
  uint32_t u = __builtin_bit_cast(uint32_t, f);
  u += 0x7fffu + ((u >> 16) & 1u);
  return (u16)(u >> 16);
}
__device__ __forceinline__ float bf2f(u16 h){
  uint32_t u = ((uint32_t)h) << 16;
  return __builtin_bit_cast(float, u);
}
__device__ __forceinline__ uint32_t cvtpk(float lo, float hi){
  uint32_t r;
  asm("v_cvt_pk_bf16_f32 %0, %1, %2" : "=v"(r) : "v"(lo), "v"(hi));
  return r;
}
__device__ __forceinline__ bf16x8 ld8(const u16* p){
  return __builtin_bit_cast(bf16x8, *(const ushort8*)p);
}
__device__ __forceinline__ void gload16(const void* g, void* l){
  __builtin_amdgcn_global_load_lds((__attribute__((address_space(1))) void*)(void*)g,
                                   (__attribute__((address_space(3))) void*)l, 16, 0, 0);
}

// ---------------- fused preprocessing: conv8 | tr(qkv_w) | tr(proj_w) | relconv ----------------

__device__ __forceinline__ void tr_body(const float* __restrict__ in, u16* __restrict__ out,
                                        int R, int Cc, int bx, int by, int t, float* tile /*64x65*/){
  int r0 = bx*64, c0 = by*64;
  int c = t & 63, r4 = t >> 6;
  for (int i = 0; i < 16; ++i)
    tile[(r4 + i*4)*65 + c] = in[(size_t)(r0 + r4 + i*4)*Cc + c0 + c];
  __syncthreads();
  for (int i = 0; i < 16; ++i){
    int rr = r4 + i*4;
    out[(size_t)(c0 + rr)*R + r0 + c] = f2bf(tile[c*65 + rr]);
  }
}

__global__ __launch_bounds__(256) void k_prep(const float* __restrict__ X32,
                                              const float* __restrict__ qkvw,
                                              const float* __restrict__ projw,
                                              const float* __restrict__ rposh,
                                              const float* __restrict__ rposw,
                                              u16* __restrict__ Xb, u16* __restrict__ W1T,
                                              u16* __restrict__ PT,
                                              u16* __restrict__ rh8, u16* __restrict__ rw8){
  __shared__ float tile[64*65];
  const int b = blockIdx.x, t = threadIdx.x;
  if (b < 1536){
    int i = b*256 + t;
    const float4* p = (const float4*)X32;
    float4 a = p[i*2], c = p[i*2+1];
    ushort8 o;
    o[0]=f2bf(a.x); o[1]=f2bf(a.y); o[2]=f2bf(a.z); o[3]=f2bf(a.w);
    o[4]=f2bf(c.x); o[5]=f2bf(c.y); o[6]=f2bf(c.z); o[7]=f2bf(c.w);
    ((ushort8*)Xb)[i] = o;
  } else if (b < 1968){
    int bb = b - 1536;
    tr_body(qkvw, W1T, 768, 2304, bb % 12, bb / 12, t, tile);
  } else if (b < 2112){
    int bb = b - 1968;
    tr_body(projw, PT, 768, 768, bb % 12, bb / 12, t, tile);
  } else {
    int i = (b - 2112)*256 + t;          // [0,16384)
    if (i < 8192)      rh8[i] = f2bf(i < 8128 ? rposh[i]*8.0f : 0.0f);
    else { int j = i - 8192; rw8[j] = f2bf(j < 8128 ? rposw[j]*8.0f : 0.0f); }
  }
}

// ---------------- QKV GEMM: (4096x768)x(768x2304), split to Qs/Kf/Vf ----------------
// K fragment-linear:  Kf[h][kb][f=ct*2+ks][lane=lg*16+lr][e] = K[kb*64+ct*16+lr][ks*32+lg*8+e]
// V fragment-linear with PERMUTED k (pi(lg,e) = (e>>2)*16 + lg*4 + (e&3)) so the
// flash PV B-operand can be assembled IN-REGISTER from the swapped-QK^T output.

__global__ __launch_bounds__(256) void k_qkv(const u16* __restrict__ X, const u16* __restrict__ WT,
                                             const float* __restrict__ bias,
                                             u16* __restrict__ Qs, u16* __restrict__ Kf, u16* __restrict__ Vf){
  __shared__ __align__(16) u16 At[128*64];
  __shared__ __align__(16) u16 Bt[128*64];
  __shared__ __align__(16) u16 Tt[4][64*72];   // per-wave repack tile, pad 72 keeps 16B align
  const int tid = threadIdx.x, lane = tid & 63, w = tid >> 6;
  const int m0 = blockIdx.x*128, n0 = blockIdx.y*128;
  const int wr = (w >> 1)*64, wc = (w & 1)*64;
  const int lr = lane & 15, lg = lane >> 4;
  const int srcRow = w*32 + (lane >> 3);
  const int srcK   = (lane & 7)*8;
  f32x4 acc[4][4] = {};
  for (int kt = 0; kt < 12; ++kt){
    const int kbase = kt*64;
    for (int s = 0; s < 4; ++s){
      gload16(X  + (size_t)(m0 + srcRow + s*8)*768 + kbase + srcK, At + (w*32 + s*8)*64);
      gload16(WT + (size_t)(n0 + srcRow + s*8)*768 + kbase + srcK, Bt + (w*32 + s*8)*64);
    }
    __syncthreads();
    bf16x8 af[2][4], bfr[2][4];
    for (int ks = 0; ks < 2; ++ks)
      for (int i = 0; i < 4; ++i){
        af[ks][i]  = ld8(At + (wr + i*16 + lr)*64 + ks*32 + lg*8);
        bfr[ks][i] = ld8(Bt + (wc + i*16 + lr)*64 + ks*32 + lg*8);
      }
    for (int ks = 0; ks < 2; ++ks)
      for (int mi = 0; mi < 4; ++mi)
        for (int ni = 0; ni < 4; ++ni)
          acc[mi][ni] = MFMA(af[ks][mi], bfr[ks][ni], acc[mi][ni], 0, 0, 0);
    __syncthreads();
  }
  const int colbase = n0 + wc;            // 64-aligned -> s3/hh uniform per wave
  const int s3 = colbase / 768;
  const int hh = (colbase % 768) >> 6;
  const int rowbase = m0 + wr;            // 64-aligned -> kb uniform per wave
  if (s3 == 0){
    for (int mi = 0; mi < 4; ++mi)
      for (int ni = 0; ni < 4; ++ni){
        float bv = bias[colbase + ni*16 + lr];
        for (int r = 0; r < 4; ++r){
          int row = rowbase + mi*16 + lg*4 + r;
          // Q pre-scaled by head_dim^-0.5 * log2(e) so softmax runs in exp2 domain
          Qs[((size_t)hh*4096 + row)*64 + ni*16 + lr] =
              f2bf((acc[mi][ni][r] + bv)*(0.125f*1.44269504f));
        }
      }
  } else {
    u16* T = Tt[w];
    for (int mi = 0; mi < 4; ++mi)
      for (int ni = 0; ni < 4; ++ni){
        float bv = bias[colbase + ni*16 + lr];
        for (int r = 0; r < 4; ++r){
          int row_l = mi*16 + lg*4 + r, col_l = ni*16 + lr;
          u16 v = f2bf(acc[mi][ni][r] + bv);
          if (s3 == 1) T[row_l*72 + col_l] = v;     // K: [token][d]
          else         T[col_l*72 + row_l] = v;     // V: [d][token] (transposed)
        }
      }
    // same-wave LDS write->read; no cross-wave sharing, compiler inserts lgkmcnt
    const int kb = rowbase >> 6;
    u16* dst = (s3 == 1 ? Kf : Vf) + ((size_t)hh*64 + kb)*4096 + lane*8;
    if (s3 == 1){
      #pragma unroll
      for (int f = 0; f < 8; ++f){
        int a = f >> 1, ks = f & 1;
        *(ushort8*)&dst[f*512] = *(const ushort8*)&T[(a*16 + lr)*72 + ks*32 + lg*8];
      }
    } else {
      // permuted-k V fragments: elems 0-3 <- tokens ks*32+lg*4+(0..3),
      //                         elems 4-7 <- tokens ks*32+16+lg*4+(0..3)
      #pragma unroll
      for (int f = 0; f < 8; ++f){
        int a = f >> 1, ks = f & 1;
        const int rowb = (a*16 + lr)*72 + ks*32 + lg*4;
        ushort4v lo = *(const ushort4v*)&T[rowb];
        ushort4v hi = *(const ushort4v*)&T[rowb + 16];
        ushort8 o;
        o[0]=lo[0]; o[1]=lo[1]; o[2]=lo[2]; o[3]=lo[3];
        o[4]=hi[0]; o[5]=hi[1]; o[6]=hi[2]; o[7]=hi[3];
        *(ushort8*)&dst[f*512] = o;
      }
    }
  }
}

// ---------------- flash attention + fused rel bias; flat grid 768, 4 waves ----------------
// R21 = R20 (proven) + guard on the wasted final stage (kb2=62 re-staged tile 0).
// Structure: K+V LDS-staged dbuf, __syncthreads loop, scalar lazy softmax,
// in-register P via permuted-k Vf, rel_h/rel_w computed in the prologue via
// swapped-operand MFMAs into per-wave LDS tiles (stride 68, conflict-free).
// Head->XCD affinity (768 = 8*96): <=2 heads (2MB KV) per XCD L2.
// launch_bounds(256,3): arch-VGPR budget ~84; spill tripwire = FETCH_SIZE.

__global__ __launch_bounds__(256, 3) void k_flash(const u16* __restrict__ Qs, const u16* __restrict__ Kf,
                                                  const u16* __restrict__ Vf,
                                                  const u16* __restrict__ Rh8, const u16* __restrict__ Rw8,
                                                  u16* __restrict__ Ob){
  __shared__ __align__(16) u16 Kl[2][4096];       // 8KB per K tile (fragment-linear copy)
  __shared__ __align__(16) u16 Vl[2][4096];       // 8KB per V tile (permuted-k layout)
  __shared__ __align__(16) u16 RhL[4][16*68];     // per-wave rel_h[q][kh], pad 68
  __shared__ __align__(16) u16 RwL[4][16*68];     // per-wave rel_w[q][kw], pad 68
  const int tid = threadIdx.x, lane = tid & 63, w = tid >> 6;
  const int b = blockIdx.x;
  const int p = (b & 7)*96 + (b >> 3);         // head->XCD affinity remap (768 = 8*96)
  const int h = p >> 6, qb = p & 63;           // qb == image row qh
  const int lr = lane & 15, lg = lane >> 4;
  const size_t hq = (size_t)h*4096;
  const int q = qb*64 + w*16 + lr;             // this lane's q row (S^T column)

  const u16* KfH = Kf + (size_t)h*262144;      // + kb*4096
  const u16* VfH = Vf + (size_t)h*262144;

  // wave w stages 1KB chunks {2w, 2w+1} of K and V (8 chunks each, 4 waves).
  auto stage = [&](int buf, int kb){
    const u16* ks = KfH + kb*4096 + w*1024 + lane*8;
    const u16* vs = VfH + kb*4096 + w*1024 + lane*8;
    gload16(ks,       &Kl[buf][w*1024]);
    gload16(ks + 512, &Kl[buf][w*1024 + 512]);
    gload16(vs,       &Vl[buf][w*1024]);
    gload16(vs + 512, &Vl[buf][w*1024 + 512]);
  };

  stage(0, 0);                                 // start tile-0 DMA; prologue overlaps it

  const bf16x8 qf0 = ld8(Qs + (hq + q)*64 + lg*8);
  const bf16x8 qf1 = ld8(Qs + (hq + q)*64 + 32 + lg*8);

  // ---- fused rel_h: lane ends with rel_h[own q][kh=ct*16+lg*4+r] ----
  u16* RhLw = RhL[w];
  #pragma unroll
  for (int ct = 0; ct < 4; ++ct){
    f32x4 c = {};
    const u16* r0 = Rh8 + (qb + 63 - (ct*16 + lr))*64 + lg*8;
    c = MFMA(ld8(r0),      qf0, c, 0, 0, 0);
    c = MFMA(ld8(r0 + 32), qf1, c, 0, 0, 0);
    #pragma unroll
    for (int r = 0; r < 4; ++r)
      RhLw[lr*68 + ct*16 + lg*4 + r] = f2bf(c[r]);
  }
  // ---- fused rel_w band: lane holds out[c=ct2*16+lg*4+r][own q]; keep kw in [0,64) ----
  u16* RwLw = RwL[w];
  #pragma unroll
  for (int ct2 = 0; ct2 < 8; ++ct2){
    f32x4 c = {};
    const u16* r0 = Rw8 + (ct2*16 + lr)*64 + lg*8;
    c = MFMA(ld8(r0),      qf0, c, 0, 0, 0);
    c = MFMA(ld8(r0 + 32), qf1, c, 0, 0, 0);
    #pragma unroll
    for (int r = 0; r < 4; ++r){
      int kw = (w*16 + lr) + 63 - (ct2*16 + lg*4 + r);
      if (kw >= 0 && kw < 64) RwLw[lr*68 + kw] = f2bf(c[r]);
    }
  }
  // rel_w bias row unpacked to f32 once (same-wave LDS write->read, lgkmcnt by compiler)
  float rwf[4][4];
  #pragma unroll
  for (int ct = 0; ct < 4; ++ct){
    ushort4v t = *(const ushort4v*)&RwLw[lr*68 + ct*16 + lg*4];
    #pragma unroll
    for (int r = 0; r < 4; ++r) rwf[ct][r] = bf2f(t[r]);
  }

  float m = -1e30f, lsum = 0.f;                // lsum per-lane partial (reduced at end)
  f32x4 oacc[4] = {};                          // O^T: rows d = dt*16+lg*4+r, col q = lr

#define ITERBODY(KB, BUF)                                                     \
  {                                                                           \
    const u16* KL = Kl[BUF] + lane*8;                                         \
    const u16* VL = Vl[BUF] + lane*8;                                         \
    const float rhv = bf2f(RhLw[lr*68 + (KB)]);                               \
    f32x4 s[4];                                                               \
    _Pragma("unroll")                                                         \
    for (int ct = 0; ct < 4; ++ct){                                           \
      _Pragma("unroll")                                                       \
      for (int r = 0; r < 4; ++r) s[ct][r] = rhv + rwf[ct][r];                \
    }                                                                         \
    __builtin_amdgcn_s_setprio(1);                                            \
    _Pragma("unroll")                                                         \
    for (int ct = 0; ct < 4; ++ct){                                           \
      s[ct] = MFMA(ld8(KL + (ct*2)*512),   qf0, s[ct], 0, 0, 0);              \
      s[ct] = MFMA(ld8(KL + (ct*2+1)*512), qf1, s[ct], 0, 0, 0);              \
    }                                                                         \
    __builtin_amdgcn_s_setprio(0);                                            \
    /* lane-local max over own 16 values */                                   \
    float pm0 = fmaxf(fmaxf(s[0][0], s[0][1]), fmaxf(fmaxf(s[0][2], s[0][3]), \
                      fmaxf(s[1][0], s[1][1])));                              \
    float pm1 = fmaxf(fmaxf(s[1][2], s[1][3]), fmaxf(fmaxf(s[2][0], s[2][1]), \
                      fmaxf(s[2][2], s[2][3])));                              \
    float pm2 = fmaxf(fmaxf(s[3][0], s[3][1]), fmaxf(s[3][2], s[3][3]));      \
    float pm = fmaxf(fmaxf(pm0, pm1), pm2);                                   \
    /* lazy rescale: cross-lane reduce only when some row max grew */         \
    if (__any(pm > m)){                                                       \
      pm = fmaxf(pm, __shfl_xor(pm, 16, 64));                                 \
      pm = fmaxf(pm, __shfl_xor(pm, 32, 64));                                 \
      const float nm = fmaxf(m, pm);                                          \
      const float corr = EXP2(m - nm);                                        \
      m = nm;                                                                 \
      lsum *= corr;                                                           \
      _Pragma("unroll")                                                       \
      for (int dt = 0; dt < 4; ++dt)                                          \
        _Pragma("unroll")                                                     \
        for (int r = 0; r < 4; ++r) oacc[dt][r] *= corr;                      \
    }                                                                         \
    float rs = 0.f;                                                           \
    _Pragma("unroll")                                                         \
    for (int ct = 0; ct < 4; ++ct){                                           \
      _Pragma("unroll")                                                       \
      for (int r = 0; r < 4; ++r){                                            \
        float p2 = EXP2(s[ct][r] - m);                                        \
        s[ct][r] = p2; rs += p2;                                              \
      }                                                                       \
    }                                                                         \
    lsum += rs;   /* per-lane partial; no shfl here */                        \
    /* P^T B-fragments in-register (k-permuted to match Vf layout) */         \
    uint4v u0, u1;                                                            \
    u0[0] = cvtpk(s[0][0], s[0][1]); u0[1] = cvtpk(s[0][2], s[0][3]);         \
    u0[2] = cvtpk(s[1][0], s[1][1]); u0[3] = cvtpk(s[1][2], s[1][3]);         \
    u1[0] = cvtpk(s[2][0], s[2][1]); u1[1] = cvtpk(s[2][2], s[2][3]);         \
    u1[2] = cvtpk(s[3][0], s[3][1]); u1[3] = cvtpk(s[3][2], s[3][3]);         \
    bf16x8 pa0 = __builtin_bit_cast(bf16x8, u0);                              \
    bf16x8 pa1 = __builtin_bit_cast(bf16x8, u1);                              \
    __builtin_amdgcn_s_setprio(1);                                            \
    _Pragma("unroll")                                                         \
    for (int dt = 0; dt < 4; ++dt){                                           \
      oacc[dt] = MFMA(ld8(VL + (dt*2)*512),   pa0, oacc[dt], 0, 0, 0);        \
      oacc[dt] = MFMA(ld8(VL + (dt*2+1)*512), pa1, oacc[dt], 0, 0, 0);        \
    }                                                                         \
    __builtin_amdgcn_s_setprio(0);                                            \
  }

  __syncthreads();                     // drains vmcnt -> tile 0 ready
  for (int kb2 = 0; kb2 < 64; kb2 += 2){
    stage(1, (kb2 + 1) & 63);          // issue next-tile loads (overlap compute)
    ITERBODY(kb2, 0)
    __syncthreads();                   // buf1 staged + all waves done with buf0
    if (kb2 < 62) stage(0, kb2 + 2);   // skip useless final re-stage of tile 0
    ITERBODY(kb2 + 1, 1)
    __syncthreads();
  }
#undef ITERBODY

  // epilogue: single cross-lane sum reduce of the per-lane lsum partials
  lsum += __shfl_xor(lsum, 16, 64);
  lsum += __shfl_xor(lsum, 32, 64);
  const float inv = 1.0f / lsum;
  #pragma unroll
  for (int dt = 0; dt < 4; ++dt){
    ushort4v pk;
    #pragma unroll
    for (int r = 0; r < 4; ++r) pk[r] = f2bf(oacc[dt][r]*inv);
    *(ushort4v*)&Ob[(size_t)q*768 + h*64 + dt*16 + lg*4] = pk;
  }
}

// ---------------- proj GEMM: (4096x768)x(768x768) + b -> f32 out ----------------
// R21: 64x128 tile (was 128x128) -> grid 384 blocks (was 192 = 0.75/CU, the
// worst-occupancy kernel in the pipeline). Wave w owns the 32x64 quadrant
// (wr=(w>>1)*32, wc=(w&1)*64), acc 2x4 fragments. Staging keeps the proven
// wave-uniform-LDS-dest + lane-linear-global-src pattern.

__global__ __launch_bounds__(256) void k_proj(const u16* __restrict__ A, const u16* __restrict__ WT,
                                              const float* __restrict__ bias, float* __restrict__ out){
  __shared__ __align__(16) u16 At[64*64];
  __shared__ __align__(16) u16 Bt[128*64];
  const int tid = threadIdx.x, lane = tid & 63, w = tid >> 6;
  const int m0 = blockIdx.x*64, n0 = blockIdx.y*128;
  const int wr = (w >> 1)*32, wc = (w & 1)*64;
  const int lr = lane & 15, lg = lane >> 4;
  const int srcRow8 = lane >> 3;          // 0..7
  const int srcK    = (lane & 7)*8;
  f32x4 acc[2][4] = {};
  for (int kt = 0; kt < 12; ++kt){
    const int kbase = kt*64;
    for (int s = 0; s < 2; ++s)
      gload16(A + (size_t)(m0 + w*16 + s*8 + srcRow8)*768 + kbase + srcK, At + (w*16 + s*8)*64);
    for (int s = 0; s < 4; ++s)
      gload16(WT + (size_t)(n0 + w*32 + s*8 + srcRow8)*768 + kbase + srcK, Bt + (w*32 + s*8)*64);
    __syncthreads();
    bf16x8 af[2][2], bfr[2][4];
    for (int ks = 0; ks < 2; ++ks){
      for (int i = 0; i < 2; ++i)
        af[ks][i]  = ld8(At + (wr + i*16 + lr)*64 + ks*32 + lg*8);
      for (int i = 0; i < 4; ++i)
        bfr[ks][i] = ld8(Bt + (wc + i*16 + lr)*64 + ks*32 + lg*8);
    }
    for (int ks = 0; ks < 2; ++ks)
      for (int mi = 0; mi < 2; ++mi)
        for (int ni = 0; ni < 4; ++ni)
          acc[mi][ni] = MFMA(af[ks][mi], bfr[ks][ni], acc[mi][ni], 0, 0, 0);
    __syncthreads();
  }
  for (int mi = 0; mi < 2; ++mi)
    for (int ni = 0; ni < 4; ++ni){
      int col = n0 + wc + ni*16 + lr;
      float bv = bias[col];
      for (int r = 0; r < 4; ++r){
        int row = m0 + wr + mi*16 + lg*4 + r;
        out[(size_t)row*768 + col] = acc[mi][ni][r] + bv;
      }
    }
}

// ---------------- launch ----------------

extern "C" void kernel_launch(void* const* d_in, const int* in_sizes, int n_in,
                              void* d_out, int out_size, void* d_ws, size_t ws_size,
                              hipStream_t stream){
  const float* X32   = (const float*)d_in[0];
  const float* qkvw  = (const float*)d_in[1];
  const float* qkvb  = (const float*)d_in[2];
  const float* projw = (const float*)d_in[3];
  const float* projb = (const float*)d_in[4];
  const float* rposh = (const float*)d_in[5];
  const float* rposw = (const float*)d_in[6];

  u16* Xb  = (u16*)d_ws;            // 4096*768
  u16* W1T = Xb  + 3145728;         // 2304*768
  u16* PT  = W1T + 1769472;         // 768*768
  u16* Rh8 = PT  + 589824;          // 128*64 (padded)
  u16* Rw8 = Rh8 + 8192;            // 128*64 (padded)
  u16* Qs  = Rw8 + 8192;            // 12*4096*64 (pre-scaled by 1/8 * log2e)
  u16* Kf  = Qs  + 3145728;         // fragment-linear K [12][64][8][64][8]
  u16* Vf  = Kf  + 3145728;         // fragment-linear V^T, k-permuted [12][64][8][64][8]
  u16* Ob  = Vf  + 3145728;         // [4096][768]
  float* out = (float*)d_out;

  k_prep <<<2176, 256, 0, stream>>>(X32, qkvw, projw, rposh, rposw, Xb, W1T, PT, Rh8, Rw8);
  k_qkv  <<<dim3(32, 18), 256, 0, stream>>>(Xb, W1T, qkvb, Qs, Kf, Vf);
  k_flash<<<768, 256, 0, stream>>>(Qs, Kf, Vf, Rh8, Rw8, Ob);
  k_proj <<<dim3(64, 6), 256, 0, stream>>>(Ob, PT, projb, out);
}